// Round 1
// baseline (1660.617 us; speedup 1.0000x reference)
//
#include <hip/hip_runtime.h>
#include <math.h>

#define BB 128
#define T2 2050
#define TT 2049
#define HH 64
#define GG 448   // 7*H
#define KK 100
#define NE 103   // K+3
#define TCHUNK 128
#define NCHUNK 17   // ceil(2049/128)

#define LOG2E 1.44269504088896340736f
#define LN2   0.69314718055994530942f

// ---- fast transcendentals (native v_exp_f32 / v_log_f32 / v_rcp_f32) ----
__device__ __forceinline__ float frcp(float x) { return __builtin_amdgcn_rcpf(x); }

__device__ __forceinline__ float sigmoid_fast(float x) {
    return frcp(1.f + exp2f(-x * LOG2E));
}
__device__ __forceinline__ float tanh_fast(float x) {
    float e = exp2f(x * (2.f * LOG2E));
    return 1.f - 2.f * frcp(1.f + e);
}
__device__ __forceinline__ float softplus_fast(float x) {
    float t = exp2f(-fabsf(x) * LOG2E);
    return fmaxf(x, 0.f) + LN2 * log2f(1.f + t);
}
__device__ __forceinline__ float expn_fast(float x) {   // e^x
    return exp2f(x * LOG2E);
}

// pre_emb[e][t] = sum_k in_emb[e][k] * Wx[k][t] + bias[t]   (103 x 448)
__global__ void pre_emb_kernel(const float* __restrict__ in_emb,
                               const float* __restrict__ Wx,
                               const float* __restrict__ bias,
                               float* __restrict__ pre_emb) {
    int e = blockIdx.x;
    int t = threadIdx.x;
    float acc = bias[t];
#pragma unroll
    for (int k = 0; k < HH; ++k)
        acc = fmaf(in_emb[e * HH + k], Wx[k * GG + t], acc);
    pre_emb[e * GG + t] = acc;
}

__device__ __forceinline__ float dot64(const float* __restrict__ hs,
                                       const float* __restrict__ w) {
    const float4* h4 = (const float4*)hs;
    float a0 = 0.f, a1 = 0.f, a2 = 0.f, a3 = 0.f;
#pragma unroll
    for (int k4 = 0; k4 < HH / 4; ++k4) {
        float4 hv = h4[k4];
        a0 = fmaf(hv.x, w[4 * k4 + 0], a0);
        a1 = fmaf(hv.y, w[4 * k4 + 1], a1);
        a2 = fmaf(hv.z, w[4 * k4 + 2], a2);
        a3 = fmaf(hv.w, w[4 * k4 + 3], a3);
    }
    return (a0 + a1) + (a2 + a3);
}

// One block per batch row; 7 waves, ONE barrier per step.
//  - wave w owns gate g=w (columns w*64..w*64+63), Wh column in registers.
//  - state update (c/cb/h) is computed REDUNDANTLY by every wave (lane i owns
//    element i) so the old narrow 64-thread phase + 2nd barrier disappear.
//  - each wave writes h into its own private LDS slice h_sw[w] and reads it
//    back wave-synchronously (no barrier; lgkmcnt only) for the GEMV.
//  - gbuf is double-buffered: write gbuf[(t+1)&1] / read gbuf[t&1]; the single
//    end-of-step barrier separates all RAW and WAR pairs.
//  - wave 6 stores exp(-softplus(gd)*dt_{t+1}) directly (dt is known a step
//    ahead), removing one exp2 from the per-step critical chain.
//  - h history is stored into out[b,t,0:64] (unused until logits_kernel
//    overwrites the full row), so no extra workspace is needed.
__launch_bounds__(GG, 1)
__global__ void scan_kernel(const int* __restrict__ event,
                            const float* __restrict__ dtime,
                            const float* __restrict__ pre_emb,
                            const float* __restrict__ Wh,
                            float* __restrict__ out) {
    const int b    = blockIdx.x;
    const int tid  = threadIdx.x;
    const int w    = tid >> 6;
    const int lane = tid & 63;

    __shared__ __align__(16) float gbuf[2][GG];
    __shared__ __align__(16) float h_sw[7][HH];

    float wcol[HH];
#pragma unroll
    for (int k = 0; k < HH; ++k) wcol[k] = Wh[k * GG + tid];

    const int*   ev_row  = event + b * T2;
    const float* dt_row  = dtime + b * T2;
    float*       out_row = out + (size_t)b * TT * KK;

    // preloop: g_0 = act(pre_emb[ev_0])  (h_{-1} = 0)
    {
        int   ev0 = ev_row[0];
        float pe0 = pre_emb[ev0 * GG + tid];
        float dt0 = dt_row[1];
        float v0;
        if (w == 2)      v0 = tanh_fast(pe0);
        else if (w == 6) v0 = expn_fast(-softplus_fast(pe0) * dt0);
        else             v0 = sigmoid_fast(pe0);
        gbuf[0][tid] = v0;
    }

    // pipelines: pe_cur = pre_emb row for step t+1; evn = event for step t+2;
    // dt_cur = dt for step t+1 (consumed by wave 6 when computing g_{t+1}).
    float pe_cur = pre_emb[ev_row[1] * GG + tid];
    int   evn    = ev_row[2];
    float dt_cur = dt_row[2];

    float c = 0.f, cb = 0.f;
    __syncthreads();

    for (int t = 0; t < TT; ++t) {
        const bool more = (t < TT - 1);
        float pe_nxt = 0.f, dt_new = 0.f;
        int   ev_new = 0;
        if (more) {
            // issue next-step prefetches first: global/scalar latency overlaps
            // the state phase + GEMV below
            pe_nxt = pre_emb[evn * GG + tid];
            int tn = (t + 3 < T2) ? (t + 3) : (T2 - 1);
            ev_new = ev_row[tn];
            dt_new = dt_row[tn];
        }

        // ---- state phase (all waves, redundant; lane i owns element i) ----
        const float* gb = gbuf[t & 1];
        const float gi  = gb[lane];
        const float gf  = gb[HH + lane];
        const float gz  = gb[2 * HH + lane];
        const float go  = gb[3 * HH + lane];
        const float gib = gb[4 * HH + lane];
        const float gfb = gb[5 * HH + lane];
        const float ed  = gb[6 * HH + lane];   // exp(-delta*dt), precomputed
        const float ci  = fmaf(gf, c, gi * gz);
        const float cbi = fmaf(gfb, cb, gib * gz);
        const float cn  = fmaf(ci - cbi, ed, cbi);
        const float h   = go * tanh_fast(cn);
        c  = cn;
        cb = cbi;

        // h history for the logits kernel (wave 0 only; 256B coalesced store,
        // fire-and-forget with a whole GEMV phase of slack before the barrier)
        if (tid < HH) out_row[(size_t)t * KK + tid] = h;

        // private copy for this wave's GEMV (wave-synchronous: no barrier)
        h_sw[w][lane] = h;

        if (more) {
            // ---- gates for step t+1 ----
            float acc = pe_cur + dot64(h_sw[w], wcol);
            float val;
            if (w == 2)      val = tanh_fast(acc);                        // z
            else if (w == 6) val = expn_fast(-softplus_fast(acc) * dt_cur); // exp(-delta*dt)
            else             val = sigmoid_fast(acc);                     // i,f,o,ib,fb
            gbuf[(t + 1) & 1][tid] = val;
            pe_cur = pe_nxt;
            evn    = ev_new;
            dt_cur = dt_new;
        }
        __syncthreads();
    }
}

// out[b,t,k] = softplus(dot(h[b,t,:], oe[k,:]))
// h lives in out[b,t,0:64]; each block stages its full h tile into LDS
// BEFORE writing any of those rows, so the in-place update is safe.
// thread k (<100) keeps oe[k] in registers and streams t from LDS (broadcast
// reads, conflict-free); stores are coalesced across k.
__launch_bounds__(128)
__global__ void logits_kernel(const float* __restrict__ oe,
                              float* __restrict__ out) {
    const int b   = blockIdx.x;
    const int t0  = blockIdx.y * TCHUNK;
    const int nt  = (TT - t0 < TCHUNK) ? (TT - t0) : TCHUNK;
    const int tid = threadIdx.x;

    __shared__ __align__(16) float hs[TCHUNK][HH];   // 32 KB

    float* row = out + ((size_t)b * TT + t0) * KK;

    const int n4 = nt * (HH / 4);
    for (int i4 = tid; i4 < n4; i4 += 128) {
        int tt = i4 >> 4, q = i4 & 15;
        ((float4*)&hs[tt][0])[q] = ((const float4*)(row + (size_t)tt * KK))[q];
    }

    float wk[HH];
    if (tid < KK) {
#pragma unroll
        for (int q = 0; q < HH / 4; ++q)
            ((float4*)wk)[q] = ((const float4*)(oe + tid * HH))[q];
    }
    __syncthreads();

    if (tid < KK) {
        for (int tt = 0; tt < nt; ++tt) {
            float lg = dot64(&hs[tt][0], wk);
            row[(size_t)tt * KK + tid] = softplus_fast(lg);
        }
    }
}

extern "C" void kernel_launch(void* const* d_in, const int* in_sizes, int n_in,
                              void* d_out, int out_size, void* d_ws, size_t ws_size,
                              hipStream_t stream) {
    const int*   event  = (const int*)d_in[0];
    const float* dtime  = (const float*)d_in[1];
    const float* in_emb = (const float*)d_in[2];
    const float* Wx     = (const float*)d_in[3];
    const float* Wh     = (const float*)d_in[4];
    const float* bias   = (const float*)d_in[5];
    const float* oe     = (const float*)d_in[6];
    float*       out    = (float*)d_out;

    float* pre_emb = (float*)d_ws;  // 103*448*4 = 184,576 bytes

    pre_emb_kernel<<<NE, GG, 0, stream>>>(in_emb, Wx, bias, pre_emb);
    scan_kernel<<<BB, GG, 0, stream>>>(event, dtime, pre_emb, Wh, out);
    logits_kernel<<<dim3(BB, NCHUNK), 128, 0, stream>>>(oe, out);
}